// Round 3
// baseline (66.475 us; speedup 1.0000x reference)
//
#include <hip/hip_runtime.h>

#define COLS    65536
#define ROWS    512
#define K_RANK  58981u           /* floor(0.9*(COLS-1)); frac=0.5 -> selected set = {x > s[K_RANK]} */
#define PARTS   8
#define T1      256
#define T2      1024
#define CAPROW  4096
#define LO_F    1.23f
#define HI_F    1.34f

/* ws layout (u32 / f32 indices into d_ws):
   u[0..511]        wsCnt[row]            (zeroed by memset each launch)
   u[512..1023]     overflow flag[row]    (zeroed by memset each launch)
   u[1024..5119]    cntLow [part][row]
   u[5120..9215]    cntHigh[part][row]
   f[9216..13311]   sumHigh[part][row]
   f[16384..]       cap[row][CAPROW]      (8 MB)
*/

typedef float f4 __attribute__((ext_vector_type(4)));

__device__ __forceinline__ unsigned key_of(float x) {
    unsigned b = __float_as_uint(x);
    return (b & 0x80000000u) ? ~b : (b | 0x80000000u);
}
__device__ __forceinline__ float float_of_key(unsigned u) {
    unsigned b = (u & 0x80000000u) ? (u & 0x7FFFFFFFu) : ~u;
    return __uint_as_float(b);
}
__device__ __forceinline__ float wredF(float v) {
    #pragma unroll
    for (int o = 32; o > 0; o >>= 1) v += __shfl_down(v, o);
    return v;
}
__device__ __forceinline__ unsigned wredU(unsigned v) {
    #pragma unroll
    for (int o = 32; o > 0; o >>= 1) v += __shfl_down(v, o);
    return v;
}

/* ================= K1: stream + capture ================= */
__global__ __launch_bounds__(T1)
void k1_stream(const float* __restrict__ X, unsigned* __restrict__ wsu,
               float* __restrict__ wsf) {
    const int bid  = blockIdx.x;
    const int row  = bid >> 3;
    const int part = bid & 7;
    const int tid  = threadIdx.x;
    const int lane = tid & 63;
    const int wid  = tid >> 6;
    const f4* x4 = (const f4*)(X + (size_t)row * COLS + (size_t)part * (COLS / PARTS));

    float h0=0.f,h1=0.f,h2=0.f,h3=0.f,h4=0.f,h5=0.f,h6=0.f,h7=0.f;
    unsigned cnt = 0u, cLow = 0u, cHigh = 0u;
    float sHigh = 0.f;

#define PROC(xx) { float x_ = (xx); \
    if (x_ < LO_F) { cLow += 1u; } \
    else if (x_ >= HI_F) { sHigh += x_; cHigh += 1u; } \
    else { \
        if (cnt < 8u) { \
            switch (cnt) { \
            case 0: h0 = x_; break; case 1: h1 = x_; break; \
            case 2: h2 = x_; break; case 3: h3 = x_; break; \
            case 4: h4 = x_; break; case 5: h5 = x_; break; \
            case 6: h6 = x_; break; default: h7 = x_; break; } \
        } \
        cnt += 1u; } }

    #pragma unroll
    for (int k = 0; k < (COLS / PARTS / 4) / T1; ++k) {      /* 8 iters */
        f4 v = __builtin_nontemporal_load(&x4[tid + k * T1]);
        PROC(v.x) PROC(v.y) PROC(v.z) PROC(v.w)
    }
#undef PROC

    /* wave compaction: one atomic per wave */
    unsigned myc = (cnt < 8u) ? cnt : 8u;
    unsigned pre = myc;
    #pragma unroll
    for (int o = 1; o < 64; o <<= 1) { unsigned n = __shfl_up(pre, o); if (lane >= o) pre += n; }
    unsigned tot  = __shfl(pre, 63);
    unsigned excl = pre - myc;
    unsigned long long ov = __ballot(cnt > 8u);
    unsigned base = 0u;
    if (lane == 63) {
        base = atomicAdd(&wsu[row], tot);
        if (ov) atomicOr(&wsu[512 + row], 1u);
    }
    base = __shfl(base, 63);
    float* capRow = wsf + 16384 + (size_t)row * CAPROW;
    unsigned p = base + excl;
    if (myc > 0u && p + 0u < CAPROW) capRow[p + 0u] = h0;
    if (myc > 1u && p + 1u < CAPROW) capRow[p + 1u] = h1;
    if (myc > 2u && p + 2u < CAPROW) capRow[p + 2u] = h2;
    if (myc > 3u && p + 3u < CAPROW) capRow[p + 3u] = h3;
    if (myc > 4u && p + 4u < CAPROW) capRow[p + 4u] = h4;
    if (myc > 5u && p + 5u < CAPROW) capRow[p + 5u] = h5;
    if (myc > 6u && p + 6u < CAPROW) capRow[p + 6u] = h6;
    if (myc > 7u && p + 7u < CAPROW) capRow[p + 7u] = h7;

    /* per-part partials (deterministic order) */
    __shared__ unsigned rA[4], rB[4];
    __shared__ float rC[4];
    unsigned a = wredU(cLow), b = wredU(cHigh);
    float c = wredF(sHigh);
    if (lane == 0) { rA[wid] = a; rB[wid] = b; rC[wid] = c; }
    __syncthreads();
    if (tid == 0) {
        unsigned A = rA[0] + rA[1] + rA[2] + rA[3];
        unsigned B = rB[0] + rB[1] + rB[2] + rB[3];
        float    C = rC[0] + rC[1] + rC[2] + rC[3];
        wsu[1024 + part * ROWS + row] = A;
        wsu[5120 + part * ROWS + row] = B;
        wsf[9216 + part * ROWS + row] = C;
    }
}

/* ================= K2: select + mean ================= */
__global__ __launch_bounds__(T2)
void k2_select(const float* __restrict__ X, const unsigned* __restrict__ wsu,
               const float* __restrict__ wsf, float* __restrict__ out) {
    const int row  = blockIdx.x;
    const int tid  = threadIdx.x;
    const int lane = tid & 63;
    const int wid  = tid >> 6;

    __shared__ float    cap[CAPROW];
    __shared__ float    cand[512];
    __shared__ unsigned hist[64];
    __shared__ unsigned redU_[16];
    __shared__ float    redF_[16];
    __shared__ int      failSh;
    __shared__ unsigned capNSh, rSh, cHighSh, nCand;
    __shared__ float    sHighSh, vrSh;
    __shared__ int      selBin, fBin;
    __shared__ unsigned selBase, fBase;
    __shared__ unsigned loS, hiS;

    if (tid == 0) {
        unsigned capN = wsu[row];
        unsigned flag = wsu[512 + row];
        unsigned cl = 0u, ch = 0u;
        float sh = 0.f;
        for (int p = 0; p < PARTS; ++p) {
            cl += wsu[1024 + p * ROWS + row];
            ch += wsu[5120 + p * ROWS + row];
            sh += wsf[9216 + p * ROWS + row];
        }
        int f = (flag != 0u) || (capN > (unsigned)CAPROW) ||
                (cl > K_RANK) || (cl + capN < K_RANK + 1u);
        failSh = f; capNSh = capN; rSh = K_RANK - cl;
        cHighSh = ch; sHighSh = sh; nCand = 0u;
    }
    __syncthreads();

    const unsigned LOBITS = __float_as_uint(LO_F);

    if (!failSh) {
        const unsigned capN = capNSh;
        const float* src = wsf + 16384 + (size_t)row * CAPROW;
        for (unsigned i = tid; i < capN; i += T2) cap[i] = src[i];
        if (tid < 64) hist[tid] = 0u;
        __syncthreads();
        for (unsigned i = tid; i < capN; i += T2) {
            unsigned d = __float_as_uint(cap[i]) - LOBITS;
            atomicAdd(&hist[d >> 16], 1u);
        }
        __syncthreads();
        const unsigned r = rSh;
        if (wid == 0) {
            unsigned v = hist[lane], incl = v;
            #pragma unroll
            for (int o = 1; o < 64; o <<= 1) { unsigned n = __shfl_up(incl, o); if (lane >= o) incl += n; }
            unsigned excl = incl - v;
            if (v && excl <= r && r < incl) { selBin = lane; selBase = excl; }
        }
        __syncthreads();
        const int B = selBin;
        const unsigned j1 = r - selBase;
        if (tid < 64) hist[tid] = 0u;
        __syncthreads();
        for (unsigned i = tid; i < capN; i += T2) {
            unsigned d = __float_as_uint(cap[i]) - LOBITS;
            if ((int)(d >> 16) == B) atomicAdd(&hist[(d >> 10) & 63u], 1u);
        }
        __syncthreads();
        if (wid == 0) {
            unsigned v = hist[lane], incl = v;
            #pragma unroll
            for (int o = 1; o < 64; o <<= 1) { unsigned n = __shfl_up(incl, o); if (lane >= o) incl += n; }
            unsigned excl = incl - v;
            if (v && excl <= j1 && j1 < incl) { fBin = lane; fBase = excl; }
        }
        __syncthreads();
        const int F = fBin;
        const unsigned j2 = j1 - fBase;
        for (unsigned i = tid; i < capN; i += T2) {
            unsigned d = __float_as_uint(cap[i]) - LOBITS;
            if ((int)(d >> 16) == B && (int)((d >> 10) & 63u) == F) {
                unsigned idx = atomicAdd(&nCand, 1u);
                if (idx < 512u) cand[idx] = cap[i];
            }
        }
        __syncthreads();
        if (tid == 0 && nCand > 512u) failSh = 1;
        __syncthreads();
        if (!failSh) {
            unsigned nC = nCand;
            if (tid < (int)nC) {
                float v = cand[tid];
                unsigned lt = 0u, eq = 0u;
                for (unsigned i = 0; i < nC; ++i) {
                    float c = cand[i];
                    lt += (c < v) ? 1u : 0u;
                    eq += (c == v) ? 1u : 0u;
                }
                if (lt <= j2 && j2 < lt + eq) vrSh = v;
            }
        }
        __syncthreads();
    }

    if (failSh) {   /* generic fallback: bisection on monotone keys from global */
        const float4* x4 = (const float4*)(X + (size_t)row * COLS);
        if (tid == 0) { loS = 0u; hiS = 0xFFFFFFFFu; }
        __syncthreads();
        for (int it = 0; it < 32; ++it) {
            unsigned mid = loS + ((hiS - loS) >> 1);
            unsigned c = 0u;
            for (int i = tid; i < COLS / 4; i += T2) {
                float4 v = x4[i];
                c += (key_of(v.x) <= mid) ? 1u : 0u;
                c += (key_of(v.y) <= mid) ? 1u : 0u;
                c += (key_of(v.z) <= mid) ? 1u : 0u;
                c += (key_of(v.w) <= mid) ? 1u : 0u;
            }
            c = wredU(c);
            if (lane == 0) redU_[wid] = c;
            __syncthreads();
            if (tid == 0) {
                unsigned t = 0u;
                for (int w = 0; w < 16; ++w) t += redU_[w];
                if (t >= K_RANK + 1u) hiS = mid; else loS = mid + 1u;
            }
            __syncthreads();
        }
        if (tid == 0) vrSh = float_of_key(loS);
        __syncthreads();
    }
    __syncthreads();

    /* final mean over {x > v_r} */
    const float vr = vrSh;
    float s = 0.f;
    unsigned c = 0u;
    if (!failSh) {
        const unsigned capN = capNSh;
        for (unsigned i = tid; i < capN; i += T2) {
            float x = cap[i];
            if (x > vr) { s += x; c += 1u; }
        }
    } else {
        const float4* x4 = (const float4*)(X + (size_t)row * COLS);
        for (int i = tid; i < COLS / 4; i += T2) {
            float4 v = x4[i];
            if (v.x > vr) { s += v.x; c += 1u; }
            if (v.y > vr) { s += v.y; c += 1u; }
            if (v.z > vr) { s += v.z; c += 1u; }
            if (v.w > vr) { s += v.w; c += 1u; }
        }
    }
    s = wredF(s); c = wredU(c);
    if (lane == 0) { redF_[wid] = s; redU_[wid] = c; }
    __syncthreads();
    if (tid == 0) {
        float S = 0.f; unsigned C = 0u;
        for (int w = 0; w < 16; ++w) { S += redF_[w]; C += redU_[w]; }
        if (!failSh) { S += sHighSh; C += cHighSh; }
        out[row] = S / (float)((C > 0u) ? C : 1u);
    }
}

extern "C" void kernel_launch(void* const* d_in, const int* in_sizes, int n_in,
                              void* d_out, int out_size, void* d_ws, size_t ws_size,
                              hipStream_t stream) {
    const float* X = (const float*)d_in[0];
    float* out = (float*)d_out;
    unsigned* wsu = (unsigned*)d_ws;
    float*    wsf = (float*)d_ws;
    const int rows = in_sizes[0] / COLS;   /* 512 */
    hipMemsetAsync(d_ws, 0, 4096, stream);
    k1_stream<<<rows * PARTS, T1, 0, stream>>>(X, wsu, wsf);
    k2_select<<<rows, T2, 0, stream>>>(X, wsu, wsf, out);
}

// Round 4
// 34.916 us; speedup vs baseline: 1.9039x; 1.9039x over previous
//
#include <hip/hip_runtime.h>

#define COLS    65536
#define THREADS 512
#define K_RANK  58981u          /* floor(0.9*(COLS-1)); frac = 0.5 */
#define SLOTS   16u
#define SSTRIDE 17              /* gcd(17,32)=1 -> 2-way max bank aliasing (free) */
#define LO_F    1.23f
#define HI_F    1.34f
#define BIGF    3.0e38f

__device__ __forceinline__ unsigned key_of(float x) {
    unsigned b = __float_as_uint(x);
    return (b & 0x80000000u) ? ~b : (b | 0x80000000u);
}
__device__ __forceinline__ float float_of_key(unsigned u) {
    unsigned b = (u & 0x80000000u) ? (u & 0x7FFFFFFFu) : ~u;
    return __uint_as_float(b);
}
__device__ __forceinline__ float wredF(float v) {
    #pragma unroll
    for (int o = 32; o > 0; o >>= 1) v += __shfl_down(v, o);
    return v;
}
__device__ __forceinline__ unsigned wredU(unsigned v) {
    #pragma unroll
    for (int o = 32; o > 0; o >>= 1) v += __shfl_down(v, o);
    return v;
}
__device__ __forceinline__ unsigned wredMaxU(unsigned v) {
    #pragma unroll
    for (int o = 32; o > 0; o >>= 1) { unsigned n = __shfl_down(v, o); v = (n > v) ? n : v; }
    return v;
}
__device__ __forceinline__ unsigned wredMinU(unsigned v) {
    #pragma unroll
    for (int o = 32; o > 0; o >>= 1) { unsigned n = __shfl_down(v, o); v = (n < v) ? n : v; }
    return v;
}
__device__ __forceinline__ float wredMinF(float v) {
    #pragma unroll
    for (int o = 32; o > 0; o >>= 1) v = fminf(v, __shfl_down(v, o));
    return v;
}

__global__ __launch_bounds__(THREADS, 4)   /* VGPR<=128 -> 2 blocks/CU guaranteed */
void dtp_kernel(const float* __restrict__ X, float* __restrict__ out) {
    const int row  = blockIdx.x;
    const int tid  = threadIdx.x;
    const int lane = tid & 63;
    const int wid  = tid >> 6;
    const float4* x4 = (const float4*)(X + (size_t)row * COLS);

    __shared__ float    slot[THREADS * SSTRIDE];   /* 34816 B */
    __shared__ float    cand[128];
    __shared__ unsigned hist[64];
    __shared__ unsigned rU1[8], rU2[8], rU3[8], rU4[8];
    __shared__ float    rF1[8], rF2[8];
    __shared__ unsigned cntLowSh, capSh, cHighSh, nCand, rSh;
    __shared__ float    sHighSh, minHighSh, vrSh, tSh;
    __shared__ int      fail, selBin, fBin;
    __shared__ unsigned selBase, fBase;
    __shared__ unsigned loS, hiS;

    if (tid == 0) { fail = 0; nCand = 0u; }
    __syncthreads();

    float* ms = &slot[tid * SSTRIDE];

    /* ---------- phase 1: single streaming read, private LDS capture ---------- */
    unsigned cnt = 0u, cLow = 0u, cHigh = 0u;
    float    sHigh = 0.f, mHigh = BIGF;

#define PROC(xx) { float x_ = (xx); \
    if (x_ < LO_F) { cLow += 1u; } \
    else if (x_ >= HI_F) { sHigh += x_; cHigh += 1u; mHigh = fminf(mHigh, x_); } \
    else { if (cnt < SLOTS) ms[cnt] = x_; cnt += 1u; } }

    #pragma unroll 8
    for (int k = 0; k < COLS / 4 / THREADS; ++k) {       /* 32 iters */
        float4 v = x4[tid + k * THREADS];
        PROC(v.x) PROC(v.y) PROC(v.z) PROC(v.w)
    }
#undef PROC

    const unsigned myN = (cnt < SLOTS) ? cnt : SLOTS;
    {
        unsigned a = wredU(cLow), b = wredU(myN), mx = wredMaxU(cnt), h = wredU(cHigh);
        float    s = wredF(sHigh), mh = wredMinF(mHigh);
        if (lane == 0) { rU1[wid] = a; rU2[wid] = b; rU3[wid] = mx; rU4[wid] = h;
                         rF1[wid] = s; rF2[wid] = mh; }
    }
    __syncthreads();
    if (tid == 0) {
        unsigned CL = 0u, CP = 0u, MX = 0u, CH = 0u; float SH = 0.f, MH = BIGF;
        for (int w = 0; w < 8; ++w) {
            CL += rU1[w]; CP += rU2[w]; MX = (rU3[w] > MX) ? rU3[w] : MX;
            CH += rU4[w]; SH += rF1[w]; MH = fminf(MH, rF2[w]);
        }
        cntLowSh = CL; capSh = CP; cHighSh = CH; sHighSh = SH; minHighSh = MH;
        if (MX > SLOTS || CL > K_RANK || CL + CP < K_RANK + 1u) fail = 1;
        rSh = K_RANK - CL;
    }
    __syncthreads();

    const unsigned LOBITS = __float_as_uint(LO_F);

    /* ---------- phase 2: exact select of rank r among captured ---------- */
    if (!fail) {
        if (tid < 64) hist[tid] = 0u;
        __syncthreads();
        for (unsigned j = 0; j < myN; ++j) {
            unsigned d = __float_as_uint(ms[j]) - LOBITS;
            atomicAdd(&hist[d >> 16], 1u);
        }
        __syncthreads();
        const unsigned r = rSh;
        if (wid == 0) {
            unsigned v = hist[lane], incl = v;
            #pragma unroll
            for (int o = 1; o < 64; o <<= 1) { unsigned n = __shfl_up(incl, o); if (lane >= o) incl += n; }
            unsigned excl = incl - v;
            if (v && excl <= r && r < incl) { selBin = lane; selBase = excl; }
        }
        __syncthreads();
        const int B = selBin;
        const unsigned j1 = r - selBase;
        if (tid < 64) hist[tid] = 0u;
        __syncthreads();
        for (unsigned j = 0; j < myN; ++j) {
            unsigned d = __float_as_uint(ms[j]) - LOBITS;
            if ((int)(d >> 16) == B) atomicAdd(&hist[(d >> 10) & 63u], 1u);
        }
        __syncthreads();
        if (wid == 0) {
            unsigned v = hist[lane], incl = v;
            #pragma unroll
            for (int o = 1; o < 64; o <<= 1) { unsigned n = __shfl_up(incl, o); if (lane >= o) incl += n; }
            unsigned excl = incl - v;
            if (v && excl <= j1 && j1 < incl) { fBin = lane; fBase = excl; }
        }
        __syncthreads();
        const int F = fBin;
        const unsigned j2 = j1 - fBase;
        for (unsigned j = 0; j < myN; ++j) {
            unsigned d = __float_as_uint(ms[j]) - LOBITS;
            if ((int)(d >> 16) == B && (int)((d >> 10) & 63u) == F) {
                unsigned idx = atomicAdd(&nCand, 1u);
                if (idx < 128u) cand[idx] = ms[j];
            }
        }
        __syncthreads();
        if (tid == 0 && nCand > 128u) fail = 1;
        __syncthreads();
        if (!fail) {
            unsigned nC = nCand;
            if (tid < (int)nC) {
                float v = cand[tid];
                unsigned lt = 0u, eq = 0u;
                for (unsigned i = 0; i < nC; ++i) {
                    float c = cand[i];
                    lt += (c < v) ? 1u : 0u;
                    eq += (c == v) ? 1u : 0u;
                }
                if (lt <= j2 && j2 < lt + eq) vrSh = v;
            }
        }
        __syncthreads();
        if (!fail) {
            /* find s[K+1]: min over {capture > vr} U {minHigh}; tie-run check */
            const float vr = vrSh;
            unsigned le = 0u; float m1 = BIGF;
            for (unsigned j = 0; j < myN; ++j) {
                float x = ms[j];
                le += (x <= vr) ? 1u : 0u;
                if (x > vr) m1 = fminf(m1, x);
            }
            le = wredU(le); m1 = wredMinF(m1);
            if (lane == 0) { rU1[wid] = le; rF1[wid] = m1; }
            __syncthreads();
            if (tid == 0) {
                unsigned LE = cntLowSh; float M1 = minHighSh;
                for (int w = 0; w < 8; ++w) { LE += rU1[w]; M1 = fminf(M1, rF1[w]); }
                float vr0 = vrSh;
                float v1  = (LE >= K_RANK + 2u) ? vr0 : M1;   /* tie-run -> s[K+1]==s[K] */
                if (v1 >= BIGF) fail = 1;
                float t = vr0 + 0.5f * (v1 - vr0);            /* exact reference formula */
                if (cHighSh > 0u && t >= minHighSh) fail = 1; /* midpoint hit high region */
                tSh = t;
            }
            __syncthreads();
        }
    }
    __syncthreads();

    if (!fail) {
        /* ---------- phase 3: mean over {x > t} from capture + high partials ---------- */
        const float t = tSh;
        float s = 0.f; unsigned c = 0u;
        for (unsigned j = 0; j < myN; ++j) {
            float x = ms[j];
            if (x > t) { s += x; c += 1u; }
        }
        s = wredF(s); c = wredU(c);
        if (lane == 0) { rF1[wid] = s; rU1[wid] = c; }
        __syncthreads();
        if (tid == 0) {
            float S = sHighSh; unsigned C = cHighSh;
            for (int w = 0; w < 8; ++w) { S += rF1[w]; C += rU1[w]; }
            out[row] = S / (float)((C > 0u) ? C : 1u);
        }
    } else {
        /* ---------- fallback: exact bisection on monotone keys (full re-read) ---------- */
        if (tid == 0) { loS = 0u; hiS = 0xFFFFFFFFu; }
        __syncthreads();
        for (int it = 0; it < 32; ++it) {
            unsigned mid = loS + ((hiS - loS) >> 1);
            unsigned c = 0u;
            for (int i = tid; i < COLS / 4; i += THREADS) {
                float4 v = x4[i];
                c += (key_of(v.x) <= mid) ? 1u : 0u;
                c += (key_of(v.y) <= mid) ? 1u : 0u;
                c += (key_of(v.z) <= mid) ? 1u : 0u;
                c += (key_of(v.w) <= mid) ? 1u : 0u;
            }
            c = wredU(c);
            if (lane == 0) rU1[wid] = c;
            __syncthreads();
            if (tid == 0) {
                unsigned t = 0u;
                for (int w = 0; w < 8; ++w) t += rU1[w];
                if (t >= K_RANK + 1u) hiS = mid; else loS = mid + 1u;
            }
            __syncthreads();
        }
        {
            const unsigned kap = loS;
            unsigned c = 0u, mA = 0xFFFFFFFFu;
            for (int i = tid; i < COLS / 4; i += THREADS) {
                float4 v = x4[i];
                float vv[4] = { v.x, v.y, v.z, v.w };
                #pragma unroll
                for (int cc = 0; cc < 4; ++cc) {
                    unsigned u = key_of(vv[cc]);
                    if (u <= kap) c += 1u; else mA = (u < mA) ? u : mA;
                }
            }
            c = wredU(c); mA = wredMinU(mA);
            if (lane == 0) { rU1[wid] = c; rU2[wid] = mA; }
            __syncthreads();
            if (tid == 0) {
                unsigned tot = 0u, m = 0xFFFFFFFFu;
                for (int w = 0; w < 8; ++w) { tot += rU1[w]; m = (rU2[w] < m) ? rU2[w] : m; }
                float vk  = float_of_key(kap);
                float vk1 = (tot >= K_RANK + 2u) ? vk : float_of_key(m);
                tSh = vk + 0.5f * (vk1 - vk);
            }
            __syncthreads();
        }
        {
            const float t = tSh;
            float s = 0.f; unsigned c = 0u;
            for (int i = tid; i < COLS / 4; i += THREADS) {
                float4 v = x4[i];
                if (v.x > t) { s += v.x; c += 1u; }
                if (v.y > t) { s += v.y; c += 1u; }
                if (v.z > t) { s += v.z; c += 1u; }
                if (v.w > t) { s += v.w; c += 1u; }
            }
            s = wredF(s); c = wredU(c);
            if (lane == 0) { rF1[wid] = s; rU1[wid] = c; }
            __syncthreads();
            if (tid == 0) {
                float S = 0.f; unsigned C = 0u;
                for (int w = 0; w < 8; ++w) { S += rF1[w]; C += rU1[w]; }
                out[row] = S / (float)((C > 0u) ? C : 1u);
            }
        }
    }
}

extern "C" void kernel_launch(void* const* d_in, const int* in_sizes, int n_in,
                              void* d_out, int out_size, void* d_ws, size_t ws_size,
                              hipStream_t stream) {
    const float* X = (const float*)d_in[0];
    float* out = (float*)d_out;
    const int rows = in_sizes[0] / COLS;   /* 512 */
    dtp_kernel<<<rows, THREADS, 0, stream>>>(X, out);
}